// Round 6
// baseline (267.994 us; speedup 1.0000x reference)
//
#include <hip/hip_runtime.h>

// Problem constants (from reference): B=256, NSEL=60000, NVERTS=100000, F=3
#define B_C     256
#define NSEL_C  60000
#define NV_C    100000
#define SCAN_T  1024
#define NB1     ((NV_C + SCAN_T - 1) / SCAN_T)   // 98 scan blocks
#define NGRP    (NV_C / 4)                       // 25000 groups of 4 vertices
#define NBLK_G  ((NGRP + 255) / 256)             // 98 group-blocks per batch
#define NBLK_P  ((NSEL_C + 255) / 256)           // 235 row-blocks per batch
#define NXCD    8
#define CAP     1536                             // staged rows per block (fallback)
#define SLICE   (NSEL_C * 3)                     // floats per batch slice

typedef float f32x4 __attribute__((ext_vector_type(4)));
typedef int   i32x4 __attribute__((ext_vector_type(4)));

// ---------------- CSR build ----------------

__global__ void zero_counts_k(int* __restrict__ counts) {
    int i = blockIdx.x * blockDim.x + threadIdx.x;
    if (i < NV_C) counts[i] = 0;
}

__global__ void hist_k(const int* __restrict__ vs, int* __restrict__ counts) {
    int j = blockIdx.x * blockDim.x + threadIdx.x;
    if (j < NSEL_C) atomicAdd(&counts[vs[j]], 1);
}

__global__ __launch_bounds__(SCAN_T) void scan1_k(const int* __restrict__ counts,
                                                  int* __restrict__ partial,
                                                  int* __restrict__ blockSums) {
    __shared__ int sm[SCAN_T];
    int tid = threadIdx.x;
    int i = blockIdx.x * SCAN_T + tid;
    int v = (i < NV_C) ? counts[i] : 0;
    int val = v;
    sm[tid] = val;
    __syncthreads();
    for (int off = 1; off < SCAN_T; off <<= 1) {
        int t = (tid >= off) ? sm[tid - off] : 0;
        __syncthreads();
        val += t;
        sm[tid] = val;
        __syncthreads();
    }
    if (i < NV_C) partial[i] = val - v;           // exclusive
    if (tid == SCAN_T - 1) blockSums[blockIdx.x] = val;
}

__global__ void scan2_k(const int* __restrict__ blockSums, int* __restrict__ blockOff) {
    if (blockIdx.x == 0 && threadIdx.x == 0) {
        int run = 0;
        for (int b = 0; b < NB1; ++b) { blockOff[b] = run; run += blockSums[b]; }
    }
}

__global__ void scan3_k(const int* __restrict__ partial, const int* __restrict__ blockOff,
                        int* __restrict__ offsets, int* __restrict__ cursor) {
    int i = blockIdx.x * blockDim.x + threadIdx.x;
    if (i < NV_C) {
        int o = partial[i] + blockOff[i / SCAN_T];
        offsets[i] = o;
        cursor[i]  = o;
    }
    if (i == 0) offsets[NV_C] = NSEL_C;
}

// list[pos] = 3*j (for gather fallback); inv[j] = 3*pos (for permute path).
__global__ void fill_k(const int* __restrict__ vs, int* __restrict__ cursor,
                       int* __restrict__ list, int* __restrict__ inv) {
    int j = blockIdx.x * blockDim.x + threadIdx.x;
    if (j < NSEL_C) {
        int v = vs[j];
        int pos = atomicAdd(&cursor[v], 1);
        list[pos] = 3 * j;
        inv[j]  = 3 * pos;
    }
}

// ---------------- permute + segment-sum (main path) ----------------
// perm_k: perm[bl][inv[j]] = x[b][j]. Reads coalesced (wave = contiguous
// 768B), writes scattered 12B. Scattered STORES have no latency chain and no
// MSHR serialization (the R2-R5 gather was capped ~200us by L1-miss service
// of scattered 12B READS). XCD swizzle pins batch b (and perm slot bl) to
// XCD bl%8 in both kernels so perm stays XCD-L2/L3 local between P and S.
__global__ __launch_bounds__(256) void perm_k(const float* __restrict__ x,
                                              const int* __restrict__ inv,
                                              float* __restrict__ perm,
                                              int round_base) {
    int lin  = blockIdx.x;
    int xcd  = lin & (NXCD - 1);
    int rest = lin >> 3;
    int t    = rest % NBLK_P;
    int bl   = (rest / NBLK_P) * NXCD + xcd;     // slot within round
    int b    = round_base + bl;                  // global batch

    int j = t * 256 + threadIdx.x;
    if (j >= NSEL_C) return;
    const float* xr = x + (size_t)b * SLICE + 3 * (size_t)j;
    float v0 = xr[0], v1 = xr[1], v2 = xr[2];    // merged dwordx3, coalesced
    int ip = inv[j];                              // coalesced, L2-cached
    float* pr = perm + (size_t)bl * SLICE + ip;
    pr[0] = v0; pr[1] = v1; pr[2] = v2;           // scattered dwordx3 store
}

// segsum_k: rows for vertex v are contiguous in perm at [offsets[v],
// offsets[v+1]) — address is 3k directly, ZERO indirection. 4 vertices per
// thread, predicated accumulation; wave reads a contiguous ~7KB span
// (L3-hot, full L1 line reuse); 3x aligned f32x4 coalesced output stores.
__global__ __launch_bounds__(256) void segsum_k(const float* __restrict__ perm,
                                                const int* __restrict__ offsets,
                                                float* __restrict__ out,
                                                int round_base) {
    int lin  = blockIdx.x;
    int xcd  = lin & (NXCD - 1);
    int rest = lin >> 3;
    int t    = rest % NBLK_G;
    int bl   = (rest / NBLK_G) * NXCD + xcd;
    int b    = round_base + bl;

    int g = t * 256 + threadIdx.x;
    if (g >= NGRP) return;
    int v0 = g * 4;

    i32x4 ov = *(const i32x4*)(offsets + v0);    // 16B-aligned
    int o0 = ov.x, o1 = ov.y, o2 = ov.z, o3 = ov.w;
    int o4 = offsets[v0 + 4];

    const float* pb = perm + (size_t)bl * SLICE;

    float f00 = 0.f, f01 = 0.f, f02 = 0.f;
    float f10 = 0.f, f11 = 0.f, f12 = 0.f;
    float f20 = 0.f, f21 = 0.f, f22 = 0.f;
    float f30 = 0.f, f31 = 0.f, f32 = 0.f;

    for (int k = o0; k < o4; ++k) {
        const float* p = pb + 3 * (size_t)k;     // sequential per thread
        float p0 = p[0], p1 = p[1], p2 = p[2];
        bool s1 = (k >= o1), s2 = (k >= o2), s3 = (k >= o3);
        bool i0 = !s1, i1 = s1 && !s2, i2 = s2 && !s3, i3 = s3;
        f00 += i0 ? p0 : 0.f;  f01 += i0 ? p1 : 0.f;  f02 += i0 ? p2 : 0.f;
        f10 += i1 ? p0 : 0.f;  f11 += i1 ? p1 : 0.f;  f12 += i1 ? p2 : 0.f;
        f20 += i2 ? p0 : 0.f;  f21 += i2 ? p1 : 0.f;  f22 += i2 ? p2 : 0.f;
        f30 += i3 ? p0 : 0.f;  f31 += i3 ? p1 : 0.f;  f32 += i3 ? p2 : 0.f;
    }

    size_t ob = ((size_t)b * NV_C + v0) * 3;     // 48B multiple -> 16B aligned
    f32x4 s0v = {f00, f01, f02, f10};
    f32x4 s1v = {f11, f12, f20, f21};
    f32x4 s2v = {f22, f30, f31, f32};
    *(f32x4*)(out + ob)     = s0v;
    *(f32x4*)(out + ob + 4) = s1v;
    *(f32x4*)(out + ob + 8) = s2v;
}

// ---------------- fallback 1: LDS-staged CSR gather (R5) ----------------
__global__ __launch_bounds__(256) void gather_lds_k(const float* __restrict__ x,
                                                    const int* __restrict__ offsets,
                                                    const int* __restrict__ list,
                                                    float* __restrict__ out) {
    __shared__ float sm[CAP * 3];

    int lin  = blockIdx.x;
    int xcd  = lin & (NXCD - 1);
    int rest = lin >> 3;
    int t    = rest % NBLK_G;
    int b    = (rest / NBLK_G) * NXCD + xcd;

    int tid = threadIdx.x;
    int vA  = t * 1024;
    int vB  = min(vA + 1024, NV_C);
    int s_blk = offsets[vA];
    int e_blk = offsets[vB];
    int nk    = e_blk - s_blk;

    const float* xb = x + (size_t)b * SLICE;

    int g  = t * 256 + tid;
    int v0 = g * 4;
    int o0 = 0, o1 = 0, o2 = 0, o3 = 0, o4 = 0;
    if (g < NGRP) {
        i32x4 ov = *(const i32x4*)(offsets + v0);
        o0 = ov.x; o1 = ov.y; o2 = ov.z; o3 = ov.w;
        o4 = offsets[v0 + 4];
    }

    if (nk <= CAP) {
        for (int k0 = s_blk + tid; k0 < e_blk; k0 += 768) {
            int k1 = k0 + 256, k2 = k0 + 512;
            bool h1 = (k1 < e_blk), h2 = (k2 < e_blk);
            int e0 = list[k0];
            int e1 = h1 ? list[k1] : e0;
            int e2 = h2 ? list[k2] : e0;
            float a0 = xb[e0], a1 = xb[e0 + 1], a2 = xb[e0 + 2];
            float b0 = xb[e1], b1 = xb[e1 + 1], b2 = xb[e1 + 2];
            float c0 = xb[e2], c1 = xb[e2 + 1], c2 = xb[e2 + 2];
            int p = (k0 - s_blk) * 3;
            sm[p] = a0; sm[p + 1] = a1; sm[p + 2] = a2;
            if (h1) { int q = p + 768;  sm[q] = b0; sm[q + 1] = b1; sm[q + 2] = b2; }
            if (h2) { int q = p + 1536; sm[q] = c0; sm[q + 1] = c1; sm[q + 2] = c2; }
        }
    }
    __syncthreads();
    if (g >= NGRP) return;

    float f00 = 0.f, f01 = 0.f, f02 = 0.f;
    float f10 = 0.f, f11 = 0.f, f12 = 0.f;
    float f20 = 0.f, f21 = 0.f, f22 = 0.f;
    float f30 = 0.f, f31 = 0.f, f32 = 0.f;

    if (nk <= CAP) {
        for (int k = o0; k < o4; ++k) {
            int p = (k - s_blk) * 3;
            float p0 = sm[p], p1 = sm[p + 1], p2 = sm[p + 2];
            bool s1 = (k >= o1), s2 = (k >= o2), s3 = (k >= o3);
            bool i0 = !s1, i1 = s1 && !s2, i2 = s2 && !s3, i3 = s3;
            f00 += i0 ? p0 : 0.f;  f01 += i0 ? p1 : 0.f;  f02 += i0 ? p2 : 0.f;
            f10 += i1 ? p0 : 0.f;  f11 += i1 ? p1 : 0.f;  f12 += i1 ? p2 : 0.f;
            f20 += i2 ? p0 : 0.f;  f21 += i2 ? p1 : 0.f;  f22 += i2 ? p2 : 0.f;
            f30 += i3 ? p0 : 0.f;  f31 += i3 ? p1 : 0.f;  f32 += i3 ? p2 : 0.f;
        }
    } else {
        for (int k = o0; k < o4; ++k) {
            int eo = list[k];
            float p0 = xb[eo], p1 = xb[eo + 1], p2 = xb[eo + 2];
            bool s1 = (k >= o1), s2 = (k >= o2), s3 = (k >= o3);
            bool i0 = !s1, i1 = s1 && !s2, i2 = s2 && !s3, i3 = s3;
            f00 += i0 ? p0 : 0.f;  f01 += i0 ? p1 : 0.f;  f02 += i0 ? p2 : 0.f;
            f10 += i1 ? p0 : 0.f;  f11 += i1 ? p1 : 0.f;  f12 += i1 ? p2 : 0.f;
            f20 += i2 ? p0 : 0.f;  f21 += i2 ? p1 : 0.f;  f22 += i2 ? p2 : 0.f;
            f30 += i3 ? p0 : 0.f;  f31 += i3 ? p1 : 0.f;  f32 += i3 ? p2 : 0.f;
        }
    }

    size_t ob = ((size_t)b * NV_C + v0) * 3;
    f32x4 s0v = {f00, f01, f02, f10};
    f32x4 s1v = {f11, f12, f20, f21};
    f32x4 s2v = {f22, f30, f31, f32};
    *(f32x4*)(out + ob)     = s0v;
    *(f32x4*)(out + ob + 4) = s1v;
    *(f32x4*)(out + ob + 8) = s2v;
}

// ---------------- fallback 2: memset + atomic scatter ----------------
__global__ __launch_bounds__(256) void scatter_atomic_k(const float* __restrict__ x,
                                                        const int* __restrict__ vs,
                                                        float* __restrict__ out) {
    int j = blockIdx.x * blockDim.x + threadIdx.x;
    int b = blockIdx.y;
    if (j < NSEL_C) {
        int v = vs[j];
        const float* p = x + ((size_t)b * NSEL_C + j) * 3;
        float* q = out + ((size_t)b * NV_C + v) * 3;
        atomicAdd(q + 0, p[0]);
        atomicAdd(q + 1, p[1]);
        atomicAdd(q + 2, p[2]);
    }
}

extern "C" void kernel_launch(void* const* d_in, const int* in_sizes, int n_in,
                              void* d_out, int out_size, void* d_ws, size_t ws_size,
                              hipStream_t stream) {
    const float* x  = (const float*)d_in[0];
    const int*   vs = (const int*)d_in[1];
    float* out = (float*)d_out;

    // ws ints: counts[NV] | partial[NV] | offsets[NV+1] | cursor[NV]
    //          | blockSums[NB1] | blockOff[NB1] | list[NSEL] | inv[NSEL]
    //          | (16B pad) | perm floats [NBR * SLICE]
    const size_t base_ints = (size_t)4 * NV_C + 1 + 2 * NB1 + 2 * NSEL_C;
    const size_t perm_off  = (base_ints + 3) & ~(size_t)3;   // 16B-align

    // Largest round size (batches) whose perm slab fits; cap at 64 for L3
    // residency between perm_k and segsum_k.
    int NBR = 0;
    for (int cand = 64; cand >= 8; cand >>= 1) {
        size_t need = (perm_off + (size_t)cand * SLICE) * sizeof(int);
        if (ws_size >= need) { NBR = cand; break; }
    }

    if (ws_size >= base_ints * sizeof(int)) {
        int* w        = (int*)d_ws;
        int* counts   = w;
        int* partial  = w + NV_C;
        int* offsets  = w + 2 * NV_C;          // NV_C + 1 entries
        int* cursor   = w + 3 * NV_C + 1;
        int* blockSums= w + 4 * NV_C + 1;
        int* blockOff = blockSums + NB1;
        int* list     = blockOff + NB1;
        int* inv      = list + NSEL_C;
        float* perm   = (float*)(w + perm_off);

        zero_counts_k<<<(NV_C + 255) / 256, 256, 0, stream>>>(counts);
        hist_k<<<(NSEL_C + 255) / 256, 256, 0, stream>>>(vs, counts);
        scan1_k<<<NB1, SCAN_T, 0, stream>>>(counts, partial, blockSums);
        scan2_k<<<1, 64, 0, stream>>>(blockSums, blockOff);
        scan3_k<<<(NV_C + 255) / 256, 256, 0, stream>>>(partial, blockOff, offsets, cursor);
        fill_k<<<(NSEL_C + 255) / 256, 256, 0, stream>>>(vs, cursor, list, inv);

        if (NBR > 0) {
            int rounds = B_C / NBR;
            for (int r = 0; r < rounds; ++r) {
                perm_k<<<NBR * NBLK_P, 256, 0, stream>>>(x, inv, perm, r * NBR);
                segsum_k<<<NBR * NBLK_G, 256, 0, stream>>>(perm, offsets, out, r * NBR);
            }
        } else {
            gather_lds_k<<<B_C * NBLK_G, 256, 0, stream>>>(x, offsets, list, out);
        }
    } else {
        hipMemsetAsync(d_out, 0, (size_t)out_size * sizeof(float), stream);
        dim3 grid((NSEL_C + 255) / 256, B_C);
        scatter_atomic_k<<<grid, 256, 0, stream>>>(x, vs, out);
    }
}